// Round 3
// baseline (322.790 us; speedup 1.0000x reference)
//
#include <hip/hip_runtime.h>
#include <stdint.h>

typedef unsigned short u16;
typedef __attribute__((ext_vector_type(8))) short bf16x8;
typedef __attribute__((ext_vector_type(4))) float f32x4;

#define BATCH 2
#define S_LEN 2048
#define DMODEL 1024
#define NH 16
#define DHEAD 64
#define MTOT 4096
#define QSCALE 0.18033688011112042f /* log2(e)/8 : folds 1/sqrt(DH) and exp->exp2 */

__device__ __forceinline__ u16 f2bf(float x) {
  union { float f; uint32_t u; } v; v.f = x;
  uint32_t r = v.u + 0x7fffu + ((v.u >> 16) & 1u);
  return (u16)(r >> 16);
}

__global__ __launch_bounds__(256) void cvt_f32_bf16(const float* __restrict__ src,
                                                    u16* __restrict__ dst, int n) {
  int i = (blockIdx.x * 256 + threadIdx.x) * 4;
  if (i + 3 < n) {
    float4 v = *(const float4*)(src + i);
    uint2 pk;
    pk.x = (uint32_t)f2bf(v.x) | ((uint32_t)f2bf(v.y) << 16);
    pk.y = (uint32_t)f2bf(v.z) | ((uint32_t)f2bf(v.w) << 16);
    *(uint2*)(dst + i) = pk;
  }
}

// C[m,n] = sum_k A[m,k]*W[n,k] (+bias). A: MTOT x DMODEL bf16, W: DMODEL x DMODEL bf16 (NT).
// mode 0: fp32 row-major out, v = acc + bias
// mode 1: bf16 out scattered (B,H,S,DH), v = (acc+bias)*scale
// mode 2: bf16 out scattered (B,H,DH,S), v = (acc+bias)*scale
__device__ __forceinline__ void gemm_body(const u16* __restrict__ A,
                                          const u16* __restrict__ W,
                                          const float* __restrict__ bias,
                                          void* __restrict__ out,
                                          int mode, float scale) {
  __shared__ u16 As[128 * 40]; // 128 rows x 32 k, pad to 40
  __shared__ u16 Bs[128 * 40];
  const int tid = threadIdx.x;
  const int m0 = blockIdx.y * 128;
  const int n0 = blockIdx.x * 128;
  const int wave = tid >> 6, lane = tid & 63;
  const int wm = (wave >> 1) * 64, wn = (wave & 1) * 64;
  const int quad = lane >> 4, l15 = lane & 15;

  f32x4 acc[4][4] = {};

  for (int kt = 0; kt < DMODEL; kt += 32) {
#pragma unroll
    for (int i = 0; i < 2; ++i) {
      int c = tid + 256 * i;
      int row = c >> 2, k8 = (c & 3) * 8;
      uint4 va = *(const uint4*)(A + (size_t)(m0 + row) * DMODEL + kt + k8);
      uint4 vb = *(const uint4*)(W + (size_t)(n0 + row) * DMODEL + kt + k8);
      *(uint4*)(&As[row * 40 + k8]) = va;
      *(uint4*)(&Bs[row * 40 + k8]) = vb;
    }
    __syncthreads();
    bf16x8 af[4], bfr[4];
#pragma unroll
    for (int bi = 0; bi < 4; ++bi)
      af[bi] = *(const bf16x8*)(&As[(wm + bi * 16 + l15) * 40 + quad * 8]);
#pragma unroll
    for (int bj = 0; bj < 4; ++bj)
      bfr[bj] = *(const bf16x8*)(&Bs[(wn + bj * 16 + l15) * 40 + quad * 8]);
#pragma unroll
    for (int bi = 0; bi < 4; ++bi)
#pragma unroll
      for (int bj = 0; bj < 4; ++bj)
        acc[bi][bj] = __builtin_amdgcn_mfma_f32_16x16x32_bf16(af[bi], bfr[bj], acc[bi][bj], 0, 0, 0);
    __syncthreads();
  }

#pragma unroll
  for (int bi = 0; bi < 4; ++bi) {
#pragma unroll
    for (int bj = 0; bj < 4; ++bj) {
      int n = n0 + wn + bj * 16 + l15;
      float bval = bias[n];
#pragma unroll
      for (int r = 0; r < 4; ++r) {
        int m = m0 + wm + bi * 16 + quad * 4 + r; // C/D layout: row = quad*4+reg, col = lane&15
        float v = acc[bi][bj][r] + bval;
        if (mode == 0) {
          ((float*)out)[(size_t)m * DMODEL + n] = v;
        } else {
          u16 bvu = f2bf(v * scale);
          int b = m >> 11, s = m & 2047;
          int h = n >> 6, d = n & 63;
          if (mode == 1)
            ((u16*)out)[(((size_t)(b * NH + h)) * S_LEN + s) * DHEAD + d] = bvu;
          else
            ((u16*)out)[(((size_t)(b * NH + h)) * DHEAD + d) * S_LEN + s] = bvu;
        }
      }
    }
  }
}

struct QKVArgs {
  const u16* w[3];
  const float* b[3];
  u16* o[3];
};

__global__ __launch_bounds__(256) void qkv_gemm(const u16* __restrict__ xb, QKVArgs a) {
  int z = blockIdx.z;
  int mode = (z == 2) ? 2 : 1;
  float scale = (z == 0) ? QSCALE : 1.0f;
  gemm_body(xb, a.w[z], a.b[z], a.o[z], mode, scale);
}

__global__ __launch_bounds__(256) void out_gemm(const u16* __restrict__ ctxb,
                                                const u16* __restrict__ wob,
                                                const float* __restrict__ bo,
                                                float* __restrict__ out) {
  gemm_body(ctxb, wob, bo, out, 0, 1.0f);
}

// Flash attention, causal. Q:(BH,S,64) pre-scaled bf16, K:(BH,S,64), Vt:(BH,64,S).
// Q-tile 64 rows/block (4 waves x 16), K-tile 128.
__global__ __launch_bounds__(256) void attn(const u16* __restrict__ Q,
                                            const u16* __restrict__ Kg,
                                            const u16* __restrict__ Vt,
                                            u16* __restrict__ ctx) {
  __shared__ u16 Ks[128 * 72];  // 128 keys x 64 dh, pad 72
  __shared__ u16 Vs[64 * 136];  // 64 dh x 128 t, pad 136
  __shared__ u16 Ps[64 * 136];  // 64 q x 128 t, pad 136
  const int tid = threadIdx.x;
  const int qt = blockIdx.x;  // 0..31
  const int bh = blockIdx.y;  // 0..31
  const int wave = tid >> 6, lane = tid & 63;
  const int quad = lane >> 4, l15 = lane & 15;

  const size_t base = (size_t)bh * S_LEN * DHEAD;
  const int qrow = qt * 64 + wave * 16 + l15;
  bf16x8 qf[2];
  qf[0] = *(const bf16x8*)(Q + base + (size_t)qrow * DHEAD + quad * 8);
  qf[1] = *(const bf16x8*)(Q + base + (size_t)qrow * DHEAD + 32 + quad * 8);

  float m_i[4], l_i[4];
  f32x4 o[4] = {};
#pragma unroll
  for (int r = 0; r < 4; ++r) { m_i[r] = -1e30f; l_i[r] = 0.f; }

  const int ktmax = qt >> 1;
  for (int kt = 0; kt <= ktmax; ++kt) {
    // cooperative staging: K tile (128 rows x 64 dh) and V^T tile (64 dh x 128 t)
#pragma unroll
    for (int i = 0; i < 4; ++i) {
      int c = tid + 256 * i;
      {
        int row = c >> 3, k8 = (c & 7) * 8;  // 8 uint4 loads per 64-wide row
        uint4 v = *(const uint4*)(Kg + base + (size_t)(kt * 128 + row) * DHEAD + k8);
        *(uint4*)(&Ks[row * 72 + k8]) = v;
      }
      {
        int d = c >> 4, t8 = (c & 15) * 8;   // 16 uint4 loads per 128-wide row
        uint4 v = *(const uint4*)(Vt + base + (size_t)d * S_LEN + kt * 128 + t8);
        *(uint4*)(&Vs[d * 136 + t8]) = v;
      }
    }
    __syncthreads();

    // S = Q K^T  (16 rows x 128 cols per wave)
    f32x4 s_acc[8];
#pragma unroll
    for (int bj = 0; bj < 8; ++bj) {
      bf16x8 kf0 = *(const bf16x8*)(&Ks[(bj * 16 + l15) * 72 + quad * 8]);
      bf16x8 kf1 = *(const bf16x8*)(&Ks[(bj * 16 + l15) * 72 + 32 + quad * 8]);
      f32x4 t = {0.f, 0.f, 0.f, 0.f};
      t = __builtin_amdgcn_mfma_f32_16x16x32_bf16(qf[0], kf0, t, 0, 0, 0);
      t = __builtin_amdgcn_mfma_f32_16x16x32_bf16(qf[1], kf1, t, 0, 0, 0);
      s_acc[bj] = t;
    }

    if (kt == ktmax) { // diagonal tile: elementwise causal mask
#pragma unroll
      for (int bj = 0; bj < 8; ++bj) {
        int kg = kt * 128 + bj * 16 + l15;
#pragma unroll
        for (int r = 0; r < 4; ++r) {
          int qg = qt * 64 + wave * 16 + quad * 4 + r;
          if (kg > qg) s_acc[bj][r] = -1e30f;
        }
      }
    }

    // online softmax (scores already include log2e/8 factor via Q scaling)
    float alpha[4];
#pragma unroll
    for (int r = 0; r < 4; ++r) {
      float mx = s_acc[0][r];
#pragma unroll
      for (int bj = 1; bj < 8; ++bj) mx = fmaxf(mx, s_acc[bj][r]);
      mx = fmaxf(mx, __shfl_xor(mx, 1, 64));
      mx = fmaxf(mx, __shfl_xor(mx, 2, 64));
      mx = fmaxf(mx, __shfl_xor(mx, 4, 64));
      mx = fmaxf(mx, __shfl_xor(mx, 8, 64));
      float mn = fmaxf(m_i[r], mx);
      alpha[r] = exp2f(m_i[r] - mn);
      m_i[r] = mn;
    }

    float rsum[4] = {0.f, 0.f, 0.f, 0.f};
#pragma unroll
    for (int bj = 0; bj < 8; ++bj) {
#pragma unroll
      for (int r = 0; r < 4; ++r) {
        float p = exp2f(s_acc[bj][r] - m_i[r]);
        rsum[r] += p;
        Ps[(wave * 16 + quad * 4 + r) * 136 + bj * 16 + l15] = f2bf(p);
      }
    }
#pragma unroll
    for (int r = 0; r < 4; ++r) {
      float s = rsum[r];
      s += __shfl_xor(s, 1, 64);
      s += __shfl_xor(s, 2, 64);
      s += __shfl_xor(s, 4, 64);
      s += __shfl_xor(s, 8, 64);
      l_i[r] = l_i[r] * alpha[r] + s;
    }
#pragma unroll
    for (int dj = 0; dj < 4; ++dj)
#pragma unroll
      for (int r = 0; r < 4; ++r) o[dj][r] *= alpha[r];

    // O += P V  (A = own 16 rows of Ps, B = Vs (k-major via transpose))
#pragma unroll
    for (int kk = 0; kk < 4; ++kk) {
      bf16x8 pf = *(const bf16x8*)(&Ps[(wave * 16 + l15) * 136 + kk * 32 + quad * 8]);
#pragma unroll
      for (int dj = 0; dj < 4; ++dj) {
        bf16x8 vf = *(const bf16x8*)(&Vs[(dj * 16 + l15) * 136 + kk * 32 + quad * 8]);
        o[dj] = __builtin_amdgcn_mfma_f32_16x16x32_bf16(pf, vf, o[dj], 0, 0, 0);
      }
    }
    __syncthreads();
  }

  const int b = bh >> 4, h = bh & 15;
#pragma unroll
  for (int r = 0; r < 4; ++r) {
    float inv = 1.0f / l_i[r];
    int srow = qt * 64 + wave * 16 + quad * 4 + r;
    size_t rowbase = ((size_t)b * S_LEN + srow) * DMODEL + h * DHEAD;
#pragma unroll
    for (int dj = 0; dj < 4; ++dj)
      ctx[rowbase + dj * 16 + l15] = f2bf(o[dj][r] * inv);
  }
}

extern "C" void kernel_launch(void* const* d_in, const int* in_sizes, int n_in,
                              void* d_out, int out_size, void* d_ws, size_t ws_size,
                              hipStream_t stream) {
  const float* x  = (const float*)d_in[0];
  const float* Wq = (const float*)d_in[1];
  const float* bq = (const float*)d_in[2];
  const float* Wk = (const float*)d_in[3];
  const float* bk = (const float*)d_in[4];
  const float* Wv = (const float*)d_in[5];
  const float* bv = (const float*)d_in[6];
  const float* Wo = (const float*)d_in[7];
  const float* bo = (const float*)d_in[8];
  float* out = (float*)d_out;

  char* ws = (char*)d_ws;
  const size_t MB = 1u << 20;
  u16* xb   = (u16*)(ws + 0);        // 8 MB (reused as ctx after QKV GEMMs)
  u16* ctxb = xb;
  u16* wqb  = (u16*)(ws + 8 * MB);
  u16* wkb  = (u16*)(ws + 10 * MB);
  u16* wvb  = (u16*)(ws + 12 * MB);
  u16* wob  = (u16*)(ws + 14 * MB);
  u16* qb   = (u16*)(ws + 16 * MB);  // 8 MB, (B,H,S,DH) pre-scaled
  u16* kb   = (u16*)(ws + 24 * MB);  // 8 MB, (B,H,S,DH)
  u16* vtb  = (u16*)(ws + 32 * MB);  // 8 MB, (B,H,DH,S)

  cvt_f32_bf16<<<4096, 256, 0, stream>>>(x, xb, MTOT * DMODEL);
  cvt_f32_bf16<<<1024, 256, 0, stream>>>(Wq, wqb, DMODEL * DMODEL);
  cvt_f32_bf16<<<1024, 256, 0, stream>>>(Wk, wkb, DMODEL * DMODEL);
  cvt_f32_bf16<<<1024, 256, 0, stream>>>(Wv, wvb, DMODEL * DMODEL);
  cvt_f32_bf16<<<1024, 256, 0, stream>>>(Wo, wob, DMODEL * DMODEL);

  QKVArgs a;
  a.w[0] = wqb; a.w[1] = wkb; a.w[2] = wvb;
  a.b[0] = bq;  a.b[1] = bk;  a.b[2] = bv;
  a.o[0] = qb;  a.o[1] = kb;  a.o[2] = vtb;
  qkv_gemm<<<dim3(DMODEL / 128, MTOT / 128, 3), 256, 0, stream>>>(xb, a);

  attn<<<dim3(S_LEN / 64, BATCH * NH), 256, 0, stream>>>(qb, kb, vtb, ctxb);

  out_gemm<<<dim3(DMODEL / 128, MTOT / 128), 256, 0, stream>>>(ctxb, wob, bo, out);
}